// Round 1
// 131.286 us; speedup vs baseline: 1.0942x; 1.0942x over previous
//
#include <hip/hip_runtime.h>
#include <hip/hip_bf16.h>

typedef __hip_bfloat16 bf16;
__device__ __forceinline__ float bf2f(bf16 v) { return __bfloat162float(v); }

typedef __attribute__((ext_vector_type(8))) short short8;
typedef __attribute__((ext_vector_type(4))) float floatx4;

#define EB_BITS 8            // 256 edge segments per bucket  (~12.8k recs)
#define VB_BITS 10           // 1024 vertex segments per bucket (~10.2k recs)
#define MAXBK   256          // bucket count ceiling (here 79+98=177)
#define F1_ITEMS 1024        // incidences per bucketize block -> 2048 records
                             // (was 4096: only 245 blocks -> 10% occupancy)

__device__ __forceinline__ int rbase(int b, int nEB, int capE, int capV) {
  return (b < nEB) ? b * capE : nEB * capE + (b - nEB) * capV;
}

// ===========================================================================
// Init per-bucket write cursors to region bases.
// ===========================================================================
__global__ void init_cursor_kernel(int* __restrict__ gcursor, int KB,
                                   int nEB, int capE, int capV) {
  const int b = threadIdx.x;
  if (b < KB) gcursor[b] = rbase(b, nEB, capE, capV);
}

// ===========================================================================
// F1: bucketize incidences into per-bucket regions with DENSE writes.
// Record = (key_local:10 | val:17). LDS staging -> coalesced runs.
// 977 blocks x 4 waves, 13.3 KB LDS -> latency hidden by TLP.
// ===========================================================================
__global__ __launch_bounds__(256) void bucketize_kernel(
    const int* __restrict__ vertex, const int* __restrict__ edges,
    int* __restrict__ gcursor, int* __restrict__ records,
    int nnz, int E, int KB, int nEB, int capE, int capV) {
  __shared__ int cnt[MAXBK];
  __shared__ int scanEx[MAXBK];
  __shared__ int bases[MAXBK];
  __shared__ int wsum4[4];
  __shared__ int staged[2 * F1_ITEMS];
  __shared__ unsigned char sbkt[2 * F1_ITEMS];

  const int tid    = threadIdx.x;
  const int lane   = tid & 63;
  const int wid    = tid >> 6;
  const int base   = blockIdx.x * F1_ITEMS;
  const int iEnd   = min(nnz, base + F1_ITEMS);

  cnt[tid] = 0;
  __syncthreads();

  int recs[8];
  int bks[8];
  int nmy = 0;
#pragma unroll
  for (int j = 0; j < 4; ++j) {
    const int i = base + tid + j * 256;
    if (i < iEnd) {
      const int e = __builtin_nontemporal_load(&edges[i]);
      const int v = __builtin_nontemporal_load(&vertex[i]);
      const int bkE = e >> EB_BITS;
      recs[nmy] = ((e & ((1 << EB_BITS) - 1)) << 17) | v;  bks[nmy] = bkE;  ++nmy;
      const int bkV = nEB + (v >> VB_BITS);
      recs[nmy] = ((v & ((1 << VB_BITS) - 1)) << 17) | e;  bks[nmy] = bkV;  ++nmy;
      atomicAdd(&cnt[bkE], 1);
      atomicAdd(&cnt[bkV], 1);
    }
  }
  __syncthreads();

  // Exclusive scan over 256 buckets: shfl wave-scan + 4-way cross-wave (2 barriers)
  const int c = cnt[tid];
  int inc = c;
#pragma unroll
  for (int d = 1; d < 64; d <<= 1) {
    int t = __shfl_up(inc, d, 64);
    if (lane >= d) inc += t;
  }
  if (lane == 63) wsum4[wid] = inc;
  __syncthreads();
  if (tid < 4) {
    int wv = wsum4[tid];
#pragma unroll
    for (int d = 1; d < 4; d <<= 1) {
      int t = __shfl_up(wv, d, 64);
      if (tid >= d) wv += t;
    }
    wsum4[tid] = wv;
  }
  __syncthreads();
  const int excl = inc - c + (wid > 0 ? wsum4[wid - 1] : 0);

  // Reserve global runs
  if (tid < KB && c > 0) bases[tid] = atomicAdd(&gcursor[tid], c);
  scanEx[tid] = excl;
  __syncthreads();
  cnt[tid] = 0;
  __syncthreads();

  // Stage records grouped by bucket
  for (int r = 0; r < nmy; ++r) {
    const int b = bks[r];
    const int p = atomicAdd(&cnt[b], 1);
    const int s = scanEx[b] + p;
    staged[s] = recs[r];
    sbkt[s] = (unsigned char)b;
  }
  __syncthreads();

  // Coalesced copy-out
  const int nrec = 2 * (iEnd - base);
  for (int s = tid; s < nrec; s += 256) {
    const int b = sbkt[s];
    records[bases[b] + (s - scanEx[b])] = staged[s];
  }
}

// ===========================================================================
// F2a: per-bucket LDS histogram + local exclusive scan.
// 1024 threads/block (grid is pinned at KB=177 -> widen blocks).
// One counter per thread; shfl wave-scan + 16-way cross-wave scan.
// ===========================================================================
__global__ __launch_bounds__(1024) void bucket_hist_kernel(
    const int* __restrict__ records, const int* __restrict__ gcursor,
    int* __restrict__ offs, int* __restrict__ btot,
    int nEB, int capE, int capV, int E, int M) {
  __shared__ int cnt[1 << VB_BITS];
  __shared__ int wsum[16];
  const int b    = blockIdx.x;
  const int tid  = threadIdx.x;
  const int lane = tid & 63;
  const int wid  = tid >> 6;

  const int base = rbase(b, nEB, capE, capV);
  const int end  = gcursor[b];

  cnt[tid] = 0;
  __syncthreads();

  for (int r = base + tid; r < end; r += 1024)
    atomicAdd(&cnt[records[r] >> 17], 1);
  __syncthreads();

  const int c = cnt[tid];
  int inc = c;
#pragma unroll
  for (int d = 1; d < 64; d <<= 1) {
    int t = __shfl_up(inc, d, 64);
    if (lane >= d) inc += t;
  }
  if (lane == 63) wsum[wid] = inc;
  __syncthreads();
  if (tid < 16) {
    int wv = wsum[tid];
#pragma unroll
    for (int d = 1; d < 16; d <<= 1) {
      int t = __shfl_up(wv, d, 64);
      if (tid >= d) wv += t;
    }
    wsum[tid] = wv;
  }
  __syncthreads();
  const int excl = inc - c + (wid > 0 ? wsum[wid - 1] : 0);

  int seg_lo, segN;
  if (b < nEB) { seg_lo = b << EB_BITS;               segN = min(E - seg_lo, 1 << EB_BITS); }
  else         { seg_lo = E + ((b - nEB) << VB_BITS); segN = min(M - seg_lo, 1 << VB_BITS); }
  if (tid < segN) offs[seg_lo + tid] = excl;
  if (tid == 0) btot[b] = wsum[15];
}

// ===========================================================================
// F2b: cross-bucket exclusive scan (KB <= 256) + offs[M] sentinel.
// ===========================================================================
__global__ __launch_bounds__(256) void bucket_scan_kernel(
    const int* __restrict__ btot, int* __restrict__ bbase,
    int* __restrict__ offs, int KB, int M) {
  __shared__ int lds[256];
  const int tid = threadIdx.x;
  const int val = (tid < KB) ? btot[tid] : 0;
  lds[tid] = val;
  __syncthreads();
  for (int off = 1; off < 256; off <<= 1) {
    int t = (tid >= off) ? lds[tid - off] : 0;
    __syncthreads();
    lds[tid] += t;
    __syncthreads();
  }
  if (tid < KB) bbase[tid] = lds[tid] - val;
  if (tid == KB - 1) offs[M] = lds[tid];   // == 2*nnz
}

// ===========================================================================
// F3: per-bucket fill into single-writer perm window (L2 write-merging).
// 1024 threads/block.
// ===========================================================================
__global__ __launch_bounds__(1024) void fill_bucket_kernel(
    const int* __restrict__ records, const int* __restrict__ gcursor,
    const int* __restrict__ bbase, int* __restrict__ offs,
    int* __restrict__ perm, int nEB, int capE, int capV, int E, int M) {
  __shared__ int cursors[1 << VB_BITS];
  const int b   = blockIdx.x;
  const int tid = threadIdx.x;

  const int base = rbase(b, nEB, capE, capV);
  const int end  = gcursor[b];
  const int bb   = bbase[b];

  int seg_lo, segN;
  if (b < nEB) { seg_lo = b << EB_BITS;               segN = min(E - seg_lo, 1 << EB_BITS); }
  else         { seg_lo = E + ((b - nEB) << VB_BITS); segN = min(M - seg_lo, 1 << VB_BITS); }

  if (tid < segN) {
    const int t = offs[seg_lo + tid] + bb;
    cursors[tid] = t;
    offs[seg_lo + tid] = t;
  }
  __syncthreads();

  for (int r = base + tid; r < end; r += 1024) {
    const int rec = records[r];
    const int p = atomicAdd(&cursors[rec >> 17], 1);
    perm[p] = rec & 0x1FFFF;
  }
}

// ===========================================================================
// MFMA GEMM: Xl[N,64] (bf16) = X[N,128] (f32) @ W[128,64] (f32).
// Block = 4 waves; 64-row tile x 64 cols; K=128 via mfma_f32_16x16x32_bf16.
// W^T staged to LDS once/block, B-fragments hoisted to registers.
// A-layout: a[j] = A[m=lane&15][k=quad*8+j]; B: b[j] = B[k=quad*8+j][n=lane&15]
// C/D: col=lane&15, row=quad*4+reg  (verified layouts, learn_hip m89/m120)
// ===========================================================================
__device__ __forceinline__ unsigned int pack_bf16x2(float lo, float hi) {
  bf16 a = __float2bfloat16(lo);
  bf16 b = __float2bfloat16(hi);
  unsigned short ua = *(unsigned short*)&a;
  unsigned short ub = *(unsigned short*)&b;
  return (unsigned int)ua | ((unsigned int)ub << 16);
}

#define XS_STRIDE 136   // ushort; 16B-aligned rows, 2-way-free fragment reads

__global__ __launch_bounds__(256) void gemm_kernel(
    const float* __restrict__ X, const float* __restrict__ W,
    bf16* __restrict__ Xl, int Nrows, int ntiles) {
  __shared__ unsigned short Ws[64 * XS_STRIDE];   // W^T: [n][k] bf16, 17.4 KB
  __shared__ unsigned short Xs[64 * XS_STRIDE];   // [m][k] bf16,     17.4 KB

  const int tid  = threadIdx.x;
  const int wave = tid >> 6;
  const int lane = tid & 63;
  const int quad = lane >> 4;
  const int l15  = lane & 15;

  // Stage W^T (8192 elements, coalesced f32 reads, scalar bf16 LDS writes)
  for (int i = tid; i < 8192; i += 256) {
    const int k = i >> 6, n = i & 63;
    bf16 h = __float2bfloat16(W[i]);
    Ws[n * XS_STRIDE + k] = *(unsigned short*)&h;
  }
  __syncthreads();

  // Hoist B fragments: b[ct][kt] = W[kt*32+quad*8+j][ct*16+l15]
  short8 bfrag[4][4];
#pragma unroll
  for (int ct = 0; ct < 4; ++ct)
#pragma unroll
    for (int kt = 0; kt < 4; ++kt)
      bfrag[ct][kt] = *(const short8*)&Ws[(ct * 16 + l15) * XS_STRIDE + kt * 32 + quad * 8];

  const int r  = tid >> 2;        // staging row 0..63
  const int c0 = (tid & 3) * 32;  // staging col group

  for (int tile = blockIdx.x; tile < ntiles; tile += gridDim.x) {
    const int row0 = tile * 64;
    // Stage 64 rows of X as bf16 (32 floats/thread: 8x float4 -> 4x uint4)
    {
      int rr = row0 + r;
      if (rr >= Nrows) rr = Nrows - 1;
      const float* src = X + (size_t)rr * 128 + c0;
      unsigned short* dst = &Xs[r * XS_STRIDE + c0];
#pragma unroll
      for (int q = 0; q < 4; ++q) {
        const float4 f0 = *(const float4*)(src + q * 8);
        const float4 f1 = *(const float4*)(src + q * 8 + 4);
        uint4 o;
        o.x = pack_bf16x2(f0.x, f0.y);
        o.y = pack_bf16x2(f0.z, f0.w);
        o.z = pack_bf16x2(f1.x, f1.y);
        o.w = pack_bf16x2(f1.z, f1.w);
        *(uint4*)(dst + q * 8) = o;
      }
    }
    __syncthreads();

    // A fragments for this wave's 16 rows
    const int m = wave * 16 + l15;
    short8 afrag[4];
#pragma unroll
    for (int kt = 0; kt < 4; ++kt)
      afrag[kt] = *(const short8*)&Xs[m * XS_STRIDE + kt * 32 + quad * 8];

    floatx4 acc[4];
#pragma unroll
    for (int ct = 0; ct < 4; ++ct) {
      acc[ct] = (floatx4){0.f, 0.f, 0.f, 0.f};
#pragma unroll
      for (int kt = 0; kt < 4; ++kt)
        acc[ct] = __builtin_amdgcn_mfma_f32_16x16x32_bf16(
            afrag[kt], bfrag[ct][kt], acc[ct], 0, 0, 0);
    }

    // Store C: row = row0 + wave*16 + quad*4 + reg, col = ct*16 + l15
    const int rbase_ = row0 + wave * 16 + quad * 4;
#pragma unroll
    for (int ct = 0; ct < 4; ++ct) {
      const int col = ct * 16 + l15;
#pragma unroll
      for (int reg = 0; reg < 4; ++reg) {
        const int row = rbase_ + reg;
        if (row < Nrows) Xl[(size_t)row * 64 + col] = __float2bfloat16(acc[ct][reg]);
      }
    }
    __syncthreads();   // before next tile restages Xs
  }
}

// ===========================================================================
// Gather 1: one wave per hyperedge. Xe[e] = degE[e]*W_edge[e] * sum_v Xl[v]
// ===========================================================================
__global__ __launch_bounds__(256) void gather_e_kernel(
    const bf16* __restrict__ Xl, const int* __restrict__ perm,
    const int* __restrict__ offs, const float* __restrict__ degE,
    const float* __restrict__ W_edge, bf16* __restrict__ Xe, int E) {
  const int gtid = blockIdx.x * 256 + threadIdx.x;
  const int e    = gtid >> 6;
  const int lane = gtid & 63;
  if (e >= E) return;

  const int beg = offs[e];
  const int end = offs[e + 1];
  float acc = 0.f;

  for (int base = beg; base < end; base += 64) {
    const int n = min(64, end - base);
    const int idx = (lane < n) ? perm[base + lane] : 0;
    int jj = 0;
    for (; jj + 4 <= n; jj += 4) {
      const int v0 = __shfl(idx, jj + 0, 64);
      const int v1 = __shfl(idx, jj + 1, 64);
      const int v2 = __shfl(idx, jj + 2, 64);
      const int v3 = __shfl(idx, jj + 3, 64);
      const float f0 = bf2f(Xl[(size_t)v0 * 64 + lane]);
      const float f1 = bf2f(Xl[(size_t)v1 * 64 + lane]);
      const float f2 = bf2f(Xl[(size_t)v2 * 64 + lane]);
      const float f3 = bf2f(Xl[(size_t)v3 * 64 + lane]);
      acc += (f0 + f1) + (f2 + f3);
    }
    for (; jj < n; ++jj) {
      const int v = __shfl(idx, jj, 64);
      acc += bf2f(Xl[(size_t)v * 64 + lane]);
    }
  }
  const float s = degE[e] * W_edge[e];
  Xe[(size_t)e * 64 + lane] = __float2bfloat16(acc * s);
}

// ===========================================================================
// Gather 2: one wave per node. out[v] = degV[v] * sum_e Xe[e]
// ===========================================================================
__global__ __launch_bounds__(256) void gather_v_kernel(
    const bf16* __restrict__ Xe, const int* __restrict__ perm,
    const int* __restrict__ offs, const float* __restrict__ degV,
    float* __restrict__ out, int N, int E) {
  const int gtid = blockIdx.x * 256 + threadIdx.x;
  const int v    = gtid >> 6;
  const int lane = gtid & 63;
  if (v >= N) return;

  const int beg = offs[E + v];
  const int end = offs[E + v + 1];
  float acc = 0.f;

  for (int base = beg; base < end; base += 64) {
    const int n = min(64, end - base);
    const int idx = (lane < n) ? perm[base + lane] : 0;
    int jj = 0;
    for (; jj + 4 <= n; jj += 4) {
      const int e0 = __shfl(idx, jj + 0, 64);
      const int e1 = __shfl(idx, jj + 1, 64);
      const int e2 = __shfl(idx, jj + 2, 64);
      const int e3 = __shfl(idx, jj + 3, 64);
      const float f0 = bf2f(Xe[(size_t)e0 * 64 + lane]);
      const float f1 = bf2f(Xe[(size_t)e1 * 64 + lane]);
      const float f2 = bf2f(Xe[(size_t)e2 * 64 + lane]);
      const float f3 = bf2f(Xe[(size_t)e3 * 64 + lane]);
      acc += (f0 + f1) + (f2 + f3);
    }
    for (; jj < n; ++jj) {
      const int e = __shfl(idx, jj, 64);
      acc += bf2f(Xe[(size_t)e * 64 + lane]);
    }
  }
  __builtin_nontemporal_store(acc * degV[v], &out[(size_t)v * 64 + lane]);
}

// ===========================================================================
extern "C" void kernel_launch(void* const* d_in, const int* in_sizes, int n_in,
                              void* d_out, int out_size, void* d_ws, size_t ws_size,
                              hipStream_t stream) {
  const float* X      = (const float*)d_in[0];
  const int*   vertex = (const int*)d_in[1];
  const int*   edges  = (const int*)d_in[2];
  const float* W      = (const float*)d_in[3];
  const float* degE   = (const float*)d_in[4];
  const float* degV   = (const float*)d_in[5];
  const float* W_edge = (const float*)d_in[6];
  float* out = (float*)d_out;

  const int nnz = in_sizes[1];
  const int E   = in_sizes[4];
  const int N   = in_sizes[5];
  const int M   = E + N;

  const int nEB = (E + (1 << EB_BITS) - 1) >> EB_BITS;
  const int nVB = (N + (1 << VB_BITS) - 1) >> VB_BITS;
  const int KB  = nEB + nVB;

  const int capE = (nnz / nEB) * 3 / 2 + 256;
  const int capV = (nnz / nVB) * 3 / 2 + 256;
  const size_t rec_total = (size_t)nEB * capE + (size_t)nVB * capV;

  char* p = (char*)d_ws;
  auto alloc = [&](size_t bytes) -> void* {
    void* r = (void*)p;
    p += (bytes + 255) & ~(size_t)255;
    return r;
  };
  int*  offs    = (int*)alloc((size_t)(M + 1) * 4);
  int*  btot    = (int*)alloc(MAXBK * 4);
  int*  bbase   = (int*)alloc(MAXBK * 4);
  int*  gcursor = (int*)alloc(MAXBK * 4);
  int*  perm    = (int*)alloc((size_t)2 * nnz * 4);
  bf16* Xe      = (bf16*)alloc((size_t)E * 64 * 2);
  // records (~12.1 MB) aliases Xl (12.8 MB): records dead before gemm runs.
  const size_t rb = rec_total * 4, xb = (size_t)N * 64 * 2;
  void* shared_region = alloc(rb > xb ? rb : xb);
  int*  records = (int*)shared_region;
  bf16* Xl      = (bf16*)shared_region;

  const int f1blocks = (nnz + F1_ITEMS - 1) / F1_ITEMS;

  init_cursor_kernel<<<1, MAXBK, 0, stream>>>(gcursor, KB, nEB, capE, capV);
  bucketize_kernel<<<f1blocks, 256, 0, stream>>>(vertex, edges, gcursor, records,
                                                 nnz, E, KB, nEB, capE, capV);
  bucket_hist_kernel<<<KB, 1024, 0, stream>>>(records, gcursor, offs, btot,
                                              nEB, capE, capV, E, M);
  bucket_scan_kernel<<<1, 256, 0, stream>>>(btot, bbase, offs, KB, M);
  fill_bucket_kernel<<<KB, 1024, 0, stream>>>(records, gcursor, bbase, offs, perm,
                                              nEB, capE, capV, E, M);

  const int ntiles = (N + 63) / 64;
  const int gblocks = ntiles < 512 ? ntiles : 512;
  gemm_kernel<<<gblocks, 256, 0, stream>>>(X, W, Xl, N, ntiles);

  gather_e_kernel<<<(E + 3) / 4, 256, 0, stream>>>(Xl, perm, offs, degE, W_edge, Xe, E);
  gather_v_kernel<<<(N + 3) / 4, 256, 0, stream>>>(Xe, perm, offs, degV, out, N, E);
}